// Round 12
// baseline (146.609 us; speedup 1.0000x reference)
//
#include <hip/hip_runtime.h>
#include <cstdint>
#include <cstddef>

typedef unsigned short u16;
typedef __attribute__((ext_vector_type(8))) short short8;
typedef __attribute__((ext_vector_type(4))) float f32x4;

#define CIN   512
#define COUT  512
#define BATCH 16
#define HWSZ  1024      // 32*32
#define PADW  34        // 32 + 2 halo

static constexpr float MOD_SCALE  = 0.044194173824159216f;   // 1/sqrt(512)
static constexpr float CONV_SCALE = 0.014731391274719739f;   // 1/sqrt(512*9)

// workspace layout (bytes)
#define WS_S    0                              // 8192 f32   (32 KB)
#define WS_DSC  (32*1024)                      // 8192 f32   (32 KB)
#define WS_WSQ  (64*1024)                      // 262144 f32 (1 MB)
#define WS_WBT  (64*1024 + 1024*1024)          // 9*512*512 bf16 (4.5 MB)
#define WS_XSP  (WS_WBT + 9*512*512*2)         // 16*34*34*512 bf16 (~18 MB)

__device__ __forceinline__ u16 f2bf(float f) {
  union { float f; uint32_t u; } v; v.f = f;
  uint32_t r = v.u + 0x7fffu + ((v.u >> 16) & 1u);   // RNE
  return (u16)(r >> 16);
}

__device__ __forceinline__ void gload16(const void* g, void* l) {
  __builtin_amdgcn_global_load_lds(
      (const __attribute__((address_space(1))) void*)g,
      (__attribute__((address_space(3))) void*)l, 16, 0, 0);
}

// ---------------- s[b,i] = mod_scale * style[b,:] . mod_w[i,:] + mod_b[i] ----------------
__global__ void k_style(const float* __restrict__ style, const float* __restrict__ mod_w,
                        const float* __restrict__ mod_b, float* __restrict__ s_out) {
  int gid  = blockIdx.x * blockDim.x + threadIdx.x;
  int w    = gid >> 6, lane = gid & 63;
  int b    = w >> 9, i = w & 511;
  const float4* st = (const float4*)(style + (size_t)b * 512);
  const float4* mw = (const float4*)(mod_w + (size_t)i * 512);
  float4 a0 = st[lane * 2], a1 = st[lane * 2 + 1];
  float4 w0 = mw[lane * 2], w1 = mw[lane * 2 + 1];
  float acc = a0.x*w0.x + a0.y*w0.y + a0.z*w0.z + a0.w*w0.w
            + a1.x*w1.x + a1.y*w1.y + a1.z*w1.z + a1.w*w1.w;
  #pragma unroll
  for (int off = 32; off; off >>= 1) acc += __shfl_xor(acc, off);
  if (lane == 0) s_out[w] = acc * MOD_SCALE + mod_b[i];
}

// ---- fused: wsq[o,i] = sum_k w^2 ; wbT[kxy][o][i] = bf16(w) ----
__global__ void k_wprep(const float* __restrict__ w, float* __restrict__ wsq,
                        u16* __restrict__ wbt) {
  int idx = blockIdx.x * 256 + threadIdx.x;          // 262144 = o*512+i
  const float* p = w + (size_t)idx * 9;
  float a = 0.f;
  #pragma unroll
  for (int kxy = 0; kxy < 9; ++kxy) {
    float v = p[kxy];
    a += v * v;
    wbt[(size_t)kxy * 262144 + idx] = f2bf(v);
  }
  wsq[idx] = a;
}

// ---------------- dscale[b,o] = conv_scale * rsqrt(cs^2 * sum_i wsq[o,i]*s[b,i]^2 + 1e-8) ----
__global__ void k_dscale(const float* __restrict__ wsq, const float* __restrict__ s,
                         float* __restrict__ dsc) {
  int gid  = blockIdx.x * blockDim.x + threadIdx.x;
  int w    = gid >> 6, lane = gid & 63;
  int b    = w >> 9, o = w & 511;
  const float4* q4 = (const float4*)(wsq + (size_t)o * 512);
  const float4* s4 = (const float4*)(s   + (size_t)b * 512);
  float4 q0 = q4[lane * 2], q1 = q4[lane * 2 + 1];
  float4 t0 = s4[lane * 2], t1 = s4[lane * 2 + 1];
  float acc = q0.x*t0.x*t0.x + q0.y*t0.y*t0.y + q0.z*t0.z*t0.z + q0.w*t0.w*t0.w
            + q1.x*t1.x*t1.x + q1.y*t1.y*t1.y + q1.z*t1.z*t1.z + q1.w*t1.w*t1.w;
  #pragma unroll
  for (int off = 32; off; off >>= 1) acc += __shfl_xor(acc, off);
  if (lane == 0)
    dsc[w] = CONV_SCALE * rsqrtf(acc * CONV_SCALE * CONV_SCALE + 1e-8f);
}

// ---------------- zero only the halo border of xs_p ----------------
__global__ void k_halo(u16* __restrict__ xsp) {
  int cell = blockIdx.x;      // 0..131 border cells of the 34x34 grid
  int b = blockIdx.y;
  int y, x;
  if (cell < 34)       { y = 0;          x = cell; }
  else if (cell < 68)  { y = 33;         x = cell - 34; }
  else if (cell < 100) { y = cell - 67;  x = 0; }    // 1..32
  else                 { y = cell - 99;  x = 33; }   // 1..32
  uint32_t* p = (uint32_t*)(xsp + ((size_t)(b * PADW + y) * PADW + x) * 512);
  p[threadIdx.x] = 0;   // 256 threads x 4B = 512 u16
}

// ---------------- xs_p[b][y+1][x+1][i] = bf16(x[b][i][y][x] * s[b][i])  (NCHW->NHWC) --------
__global__ void k_xs(const float* __restrict__ x, const float* __restrict__ s,
                     u16* __restrict__ xsp) {
  __shared__ float tile[64][33];
  int icb = blockIdx.x, y = blockIdx.y, b = blockIdx.z;
  int t = threadIdx.x;
  int i0 = icb * 64;
  int c  = t & 31;       // x coord
  int r0 = t >> 5;       // 0..7
  #pragma unroll
  for (int it = 0; it < 8; ++it) {
    int row = r0 + it * 8;                           // i_loc 0..63
    float sv = s[b * 512 + i0 + row];
    tile[row][c] = x[((size_t)(b * 512 + i0 + row)) * 1024 + y * 32 + c] * sv;
  }
  __syncthreads();
  int il = t & 63;
  int x0 = t >> 6;       // 0..3
  #pragma unroll
  for (int it = 0; it < 8; ++it) {
    int xc = x0 + it * 4;
    xsp[((size_t)((b * PADW + y + 1) * PADW) + (xc + 1)) * 512 + i0 + il] = f2bf(tile[il][xc]);
  }
}

// ---------------- implicit-GEMM conv + fused epilogue (m201 4-phase port) ----------------
// Tile 256(o) x 128(m), 4 waves (2o x 2m), PER-WAVE 128x64 (acc[8][4]),
// K=4608 in 72 tiles of 64. Each K-tile = 4 phases x 16 MFMA; phase p owns
// acc rows {2p,2p+1} (disjoint quadrants -> matrix pipe chains across barriers).
// Per phase: { 4 av ds_reads (ph0 also reads the 8 bv, held in regs all tile)
//            | 3 global_load_lds of tile t+2 } -> s_barrier -> setprio(1)
//            -> 16 MFMA -> setprio(0) -> s_barrier.
// vmcnt(12) ONCE per tile (phase 3): drains stage(t+1), leaves stage(t+2) in
// flight (T4). Ring-3 LDS (144 KB). T2 XOR swizzle. T1 XCD swizzle.
// Port/CU/tile = 96 b128 = 1152 cyc vs MFMA 1242 cyc (ratio 0.93 = m201's).
__global__ __launch_bounds__(256, 1) void k_conv(
    const u16* __restrict__ wbt, const u16* __restrict__ xsp,
    const float* __restrict__ dsc, const float* __restrict__ noise,
    const float* __restrict__ nw, const float* __restrict__ abias,
    float* __restrict__ out)
{
  __shared__ u16 Ald[3 * 16384];   // 3 x 256x64 bf16 = 96 KB (swizzled)
  __shared__ u16 Bld[3 * 8192];    // 3 x 128x64 bf16 = 48 KB (swizzled)

  const int tid  = threadIdx.x;
  const int wave = tid >> 6, lane = tid & 63;

  // T1: XCD swizzle (grid 256 = 8 XCD x 32 contiguous tiles)
  const int bid = blockIdx.x;
  const int swz = (bid & 7) * 32 + (bid >> 3);
  const int o0 = (swz >> 7) << 8;     // 0 or 256
  const int m0 = (swz & 127) << 7;    // 0..16256
  const int b  = m0 >> 10;            // uniform per block

  const int wo = (wave >> 1) * 128;   // o sub-block: 0/128
  const int wm = (wave & 1) * 64;     // m sub-block: 0/64
  const int lrow = lane & 15;
  const int lk   = (lane >> 4) * 8;
  const int rsw  = (lrow & 7) << 3;   // read-side swizzle (u16 units)
  const int kos0 = lk ^ rsw;
  const int kos1 = (32 + lk) ^ rsw;

  // staging: lane covers row (base + lane>>3), 16-B chunk (lane&7);
  // swizzled source chunk = (lane&7) ^ (row&7)  [T2 write side via global src]
  const int cc = (((lane & 7) ^ (lane >> 3)) * 8);
  // A: 8 gloads/wave (rows wave*64 + q*8), linear in q -> single base
  const u16* gAb = wbt + (size_t)(o0 + wave * 64 + (lane >> 3)) * 512 + cc;
  const int lAb = (wave * 64) * 64;                 // + q*512 (u16)
  // B: 4 gloads/wave (rows wave*32 + q*8), y/x nonlinear -> 4 ptrs
  const u16* gB[4]; int lBo[4];
  #pragma unroll
  for (int q = 0; q < 4; ++q) {
    int r = wave * 32 + q * 8 + (lane >> 3);          // 0..127
    int mg = m0 + r;
    int yy = (mg >> 5) & 31, xx = mg & 31;
    gB[q] = xsp + ((size_t)(b * PADW + yy) * PADW + xx) * 512 + cc;
    lBo[q] = (wave * 32 + q * 8) * 64;
  }

  f32x4 acc[8][4];
  #pragma unroll
  for (int i = 0; i < 8; ++i)
    #pragma unroll
    for (int j = 0; j < 4; ++j) acc[i][j] = (f32x4){0.f, 0.f, 0.f, 0.f};

  auto stgA = [&](int ks, int bufi, int q) {
    int kxy = ks >> 3, ib = (ks & 7) << 6;
    gload16(gAb + (size_t)kxy * 262144 + ib + (size_t)q * 4096,
            &Ald[bufi * 16384 + lAb + q * 512 + ib * 0]);   // dest row-major
  };
  auto stgB = [&](int ks, int bufi, int q) {
    int kxy = ks >> 3, ib = (ks & 7) << 6;
    int ky = kxy / 3, kx = kxy - ky * 3;
    gload16(gB[q] + ((ky * PADW + kx) << 9) + ib, &Bld[bufi * 8192 + lBo[q]]);
  };

#define LDA(CA, MI, KOS) (*(const short8*)&Ald[(CA) + (wo + (MI) * 16 + lrow) * 64 + (KOS)])
#define LDB(CB, NI, KOS) (*(const short8*)&Bld[(CB) + (wm + (NI) * 16 + lrow) * 64 + (KOS)])

  // phase p: av reads for mi {2p,2p+1}; 16 MFMA into acc[2p..2p+1][*]
#define PH(P, CA, STG, VMLINE)                                            \
  {                                                                       \
    short8 a0 = LDA(CA, 2*(P),   kos0), a1 = LDA(CA, 2*(P)+1, kos0);      \
    short8 a2 = LDA(CA, 2*(P),   kos1), a3 = LDA(CA, 2*(P)+1, kos1);      \
    STG;                                                                  \
    __builtin_amdgcn_s_barrier();                                         \
    __builtin_amdgcn_s_setprio(1);                                        \
    _Pragma("unroll")                                                     \
    for (int ni = 0; ni < 4; ++ni) {                                      \
      acc[2*(P)][ni]   = __builtin_amdgcn_mfma_f32_16x16x32_bf16(         \
          a0, bv0[ni], acc[2*(P)][ni], 0, 0, 0);                          \
      acc[2*(P)+1][ni] = __builtin_amdgcn_mfma_f32_16x16x32_bf16(         \
          a1, bv0[ni], acc[2*(P)+1][ni], 0, 0, 0);                        \
      acc[2*(P)][ni]   = __builtin_amdgcn_mfma_f32_16x16x32_bf16(         \
          a2, bv1[ni], acc[2*(P)][ni], 0, 0, 0);                          \
      acc[2*(P)+1][ni] = __builtin_amdgcn_mfma_f32_16x16x32_bf16(         \
          a3, bv1[ni], acc[2*(P)+1][ni], 0, 0, 0);                        \
    }                                                                     \
    __builtin_amdgcn_s_setprio(0);                                        \
    VMLINE;                                                               \
    __builtin_amdgcn_s_barrier();                                         \
  }

#define KTILE(CUR, NXT, KS2, DOSTG, VMLINE)                               \
  {                                                                       \
    const int ca = (CUR) * 16384, cb = (CUR) * 8192;                      \
    short8 bv0[4], bv1[4];                                                \
    _Pragma("unroll")                                                     \
    for (int ni = 0; ni < 4; ++ni) { bv0[ni] = LDB(cb, ni, kos0);         \
                                     bv1[ni] = LDB(cb, ni, kos1); }       \
    PH(0, ca, if (DOSTG){stgA(KS2,NXT,0);stgA(KS2,NXT,1);stgA(KS2,NXT,2);}, ) \
    PH(1, ca, if (DOSTG){stgA(KS2,NXT,3);stgA(KS2,NXT,4);stgA(KS2,NXT,5);}, ) \
    PH(2, ca, if (DOSTG){stgA(KS2,NXT,6);stgA(KS2,NXT,7);stgB(KS2,NXT,0);}, ) \
    PH(3, ca, if (DOSTG){stgB(KS2,NXT,1);stgB(KS2,NXT,2);stgB(KS2,NXT,3);}, VMLINE) \
  }

#define VM12 asm volatile("s_waitcnt vmcnt(12)" ::: "memory")
#define VM0  asm volatile("s_waitcnt vmcnt(0)"  ::: "memory")

  // prologue: tiles 0,1 staged (12 gloads each); drain tile 0, keep tile 1 in flight
  #pragma unroll
  for (int q = 0; q < 8; ++q) stgA(0, 0, q);
  #pragma unroll
  for (int q = 0; q < 4; ++q) stgB(0, 0, q);
  #pragma unroll
  for (int q = 0; q < 8; ++q) stgA(1, 1, q);
  #pragma unroll
  for (int q = 0; q < 4; ++q) stgB(1, 1, q);
  VM12;
  __builtin_amdgcn_s_barrier();

  for (int t = 0; t < 23; ++t) {
    const int k0 = t * 3;                 // tiles k0..k0+2 stage k0+2..k0+4 (<=70)
    KTILE(0, 2, k0 + 2, 1, VM12);
    KTILE(1, 0, k0 + 3, 1, VM12);
    KTILE(2, 1, k0 + 4, 1, VM12);
  }
  // tail: tiles 69,70,71
  KTILE(0, 2, 71, 1, VM12);   // tile 69: stage 71 -> buf2; drain stage(70)
  KTILE(1, 0, 0, 0, VM0);     // tile 70: drain stage(71)
  KTILE(2, 1, 0, 0, );        // tile 71
#undef KTILE
#undef PH
#undef LDA
#undef LDB
#undef VM12
#undef VM0

  // epilogue: demod*conv_scale, noise, bias, leaky(0.2)*sqrt(2)
  const float nwv = nw[0];
  const int mrow = (lane >> 4) << 2;
  #pragma unroll
  for (int mi = 0; mi < 8; ++mi) {
    #pragma unroll
    for (int ni = 0; ni < 4; ++ni) {
      int mg = m0 + wm + ni * 16 + lrow;
      int hw = mg & 1023;
      float nz = nwv * noise[b * 1024 + hw];
      #pragma unroll
      for (int r = 0; r < 4; ++r) {
        int og = o0 + wo + mi * 16 + mrow + r;
        float v = acc[mi][ni][r] * dsc[b * 512 + og] + nz + abias[og];
        v = (v > 0.f ? v : 0.2f * v) * 1.4142135623730951f;
        out[(size_t)(b * 512 + og) * 1024 + hw] = v;
      }
    }
  }
}

extern "C" void kernel_launch(void* const* d_in, const int* in_sizes, int n_in,
                              void* d_out, int out_size, void* d_ws, size_t ws_size,
                              hipStream_t stream) {
  const float* x      = (const float*)d_in[0];
  const float* style  = (const float*)d_in[1];
  const float* noise  = (const float*)d_in[2];
  const float* weight = (const float*)d_in[3];
  const float* mod_w  = (const float*)d_in[4];
  const float* mod_b  = (const float*)d_in[5];
  const float* nw     = (const float*)d_in[6];
  const float* abias  = (const float*)d_in[7];
  float* out = (float*)d_out;

  char* ws = (char*)d_ws;
  float* s_buf = (float*)(ws + WS_S);
  float* dsc   = (float*)(ws + WS_DSC);
  float* wsq   = (float*)(ws + WS_WSQ);
  u16*   wbt   = (u16*)(ws + WS_WBT);
  u16*   xsp   = (u16*)(ws + WS_XSP);

  k_halo  <<<dim3(132, 16), 256, 0, stream>>>(xsp);
  k_style <<<2048, 256, 0, stream>>>(style, mod_w, mod_b, s_buf);
  k_wprep <<<1024, 256, 0, stream>>>(weight, wsq, wbt);
  k_dscale<<<2048, 256, 0, stream>>>(wsq, s_buf, dsc);
  k_xs    <<<dim3(8, 32, 16), 256, 0, stream>>>(x, s_buf, xsp);
  k_conv  <<<256, 256, 0, stream>>>(wbt, xsp, dsc, noise, nw, abias, out);
}

// Round 13
// 146.480 us; speedup vs baseline: 1.0009x; 1.0009x over previous
//
#include <hip/hip_runtime.h>
#include <cstdint>
#include <cstddef>

typedef unsigned short u16;
typedef __attribute__((ext_vector_type(8))) short short8;
typedef __attribute__((ext_vector_type(4))) float f32x4;

#define CIN   512
#define COUT  512
#define BATCH 16
#define HWSZ  1024      // 32*32
#define PADW  34        // 32 + 2 halo

static constexpr float MOD_SCALE  = 0.044194173824159216f;   // 1/sqrt(512)
static constexpr float CONV_SCALE = 0.014731391274719739f;   // 1/sqrt(512*9)

// workspace layout (bytes)
#define WS_S    0                              // 8192 f32   (32 KB)
#define WS_DSC  (32*1024)                      // 8192 f32   (32 KB)
#define WS_WSQ  (64*1024)                      // 262144 f32 (1 MB)
#define WS_WBT  (64*1024 + 1024*1024)          // 9*512*512 bf16 (4.5 MB)
#define WS_XSP  (WS_WBT + 9*512*512*2)         // 16*34*34*512 bf16 (~18 MB)

__device__ __forceinline__ u16 f2bf(float f) {
  union { float f; uint32_t u; } v; v.f = f;
  uint32_t r = v.u + 0x7fffu + ((v.u >> 16) & 1u);   // RNE
  return (u16)(r >> 16);
}

__device__ __forceinline__ void gload16(const void* g, void* l) {
  __builtin_amdgcn_global_load_lds(
      (const __attribute__((address_space(1))) void*)g,
      (__attribute__((address_space(3))) void*)l, 16, 0, 0);
}

// ---------------- s[b,i] = mod_scale * style[b,:] . mod_w[i,:] + mod_b[i] ----------------
__global__ void k_style(const float* __restrict__ style, const float* __restrict__ mod_w,
                        const float* __restrict__ mod_b, float* __restrict__ s_out) {
  int gid  = blockIdx.x * blockDim.x + threadIdx.x;
  int w    = gid >> 6, lane = gid & 63;
  int b    = w >> 9, i = w & 511;
  const float4* st = (const float4*)(style + (size_t)b * 512);
  const float4* mw = (const float4*)(mod_w + (size_t)i * 512);
  float4 a0 = st[lane * 2], a1 = st[lane * 2 + 1];
  float4 w0 = mw[lane * 2], w1 = mw[lane * 2 + 1];
  float acc = a0.x*w0.x + a0.y*w0.y + a0.z*w0.z + a0.w*w0.w
            + a1.x*w1.x + a1.y*w1.y + a1.z*w1.z + a1.w*w1.w;
  #pragma unroll
  for (int off = 32; off; off >>= 1) acc += __shfl_xor(acc, off);
  if (lane == 0) s_out[w] = acc * MOD_SCALE + mod_b[i];
}

// ---- fused: wsq[o,i] = sum_k w^2 ; wbT[kxy][o][i] = bf16(w) ----
__global__ void k_wprep(const float* __restrict__ w, float* __restrict__ wsq,
                        u16* __restrict__ wbt) {
  int idx = blockIdx.x * 256 + threadIdx.x;          // 262144 = o*512+i
  const float* p = w + (size_t)idx * 9;
  float a = 0.f;
  #pragma unroll
  for (int kxy = 0; kxy < 9; ++kxy) {
    float v = p[kxy];
    a += v * v;
    wbt[(size_t)kxy * 262144 + idx] = f2bf(v);
  }
  wsq[idx] = a;
}

// ---------------- dscale[b,o] = conv_scale * rsqrt(cs^2 * sum_i wsq[o,i]*s[b,i]^2 + 1e-8) ----
__global__ void k_dscale(const float* __restrict__ wsq, const float* __restrict__ s,
                         float* __restrict__ dsc) {
  int gid  = blockIdx.x * blockDim.x + threadIdx.x;
  int w    = gid >> 6, lane = gid & 63;
  int b    = w >> 9, o = w & 511;
  const float4* q4 = (const float4*)(wsq + (size_t)o * 512);
  const float4* s4 = (const float4*)(s   + (size_t)b * 512);
  float4 q0 = q4[lane * 2], q1 = q4[lane * 2 + 1];
  float4 t0 = s4[lane * 2], t1 = s4[lane * 2 + 1];
  float acc = q0.x*t0.x*t0.x + q0.y*t0.y*t0.y + q0.z*t0.z*t0.z + q0.w*t0.w*t0.w
            + q1.x*t1.x*t1.x + q1.y*t1.y*t1.y + q1.z*t1.z*t1.z + q1.w*t1.w*t1.w;
  #pragma unroll
  for (int off = 32; off; off >>= 1) acc += __shfl_xor(acc, off);
  if (lane == 0)
    dsc[w] = CONV_SCALE * rsqrtf(acc * CONV_SCALE * CONV_SCALE + 1e-8f);
}

// ---------------- zero only the halo border of xs_p ----------------
__global__ void k_halo(u16* __restrict__ xsp) {
  int cell = blockIdx.x;      // 0..131 border cells of the 34x34 grid
  int b = blockIdx.y;
  int y, x;
  if (cell < 34)       { y = 0;          x = cell; }
  else if (cell < 68)  { y = 33;         x = cell - 34; }
  else if (cell < 100) { y = cell - 67;  x = 0; }    // 1..32
  else                 { y = cell - 99;  x = 33; }   // 1..32
  uint32_t* p = (uint32_t*)(xsp + ((size_t)(b * PADW + y) * PADW + x) * 512);
  p[threadIdx.x] = 0;   // 256 threads x 4B = 512 u16
}

// ---------------- xs_p[b][y+1][x+1][i] = bf16(x[b][i][y][x] * s[b][i])  (NCHW->NHWC) --------
__global__ void k_xs(const float* __restrict__ x, const float* __restrict__ s,
                     u16* __restrict__ xsp) {
  __shared__ float tile[64][33];
  int icb = blockIdx.x, y = blockIdx.y, b = blockIdx.z;
  int t = threadIdx.x;
  int i0 = icb * 64;
  int c  = t & 31;       // x coord
  int r0 = t >> 5;       // 0..7
  #pragma unroll
  for (int it = 0; it < 8; ++it) {
    int row = r0 + it * 8;                           // i_loc 0..63
    float sv = s[b * 512 + i0 + row];
    tile[row][c] = x[((size_t)(b * 512 + i0 + row)) * 1024 + y * 32 + c] * sv;
  }
  __syncthreads();
  int il = t & 63;
  int x0 = t >> 6;       // 0..3
  #pragma unroll
  for (int it = 0; it < 8; ++it) {
    int xc = x0 + it * 4;
    xsp[((size_t)((b * PADW + y + 1) * PADW) + (xc + 1)) * 512 + i0 + il] = f2bf(tile[il][xc]);
  }
}

// ---------------- implicit-GEMM conv + fused epilogue (m201 4-phase port) ----------------
// Tile 256(o) x 128(m), 4 waves (2o x 2m), PER-WAVE 128x64 (acc[8][4]),
// K=4608 in 72 tiles of 64. Each K-tile = 4 phases x 16 MFMA; phase p owns
// acc rows {2p,2p+1} (disjoint quadrants -> matrix pipe chains across barriers).
// Per phase: { 4 av ds_reads (ph0 also reads the 8 bv, held in regs all tile)
//            | 3 global_load_lds of tile t+2 } -> s_barrier -> setprio(1)
//            -> 16 MFMA -> setprio(0) -> s_barrier.
// vmcnt(12) ONCE per tile (phase 3): drains stage(t+1), leaves stage(t+2) in
// flight (T4). Ring-3 LDS (144 KB). T2 XOR swizzle. T1 XCD swizzle.
// Port/CU/tile = 96 b128 = 1152 cyc vs MFMA 1242 cyc (ratio 0.93 = m201's).
__global__ __launch_bounds__(256, 1) void k_conv(
    const u16* __restrict__ wbt, const u16* __restrict__ xsp,
    const float* __restrict__ dsc, const float* __restrict__ noise,
    const float* __restrict__ nw, const float* __restrict__ abias,
    float* __restrict__ out)
{
  __shared__ u16 Ald[3 * 16384];   // 3 x 256x64 bf16 = 96 KB (swizzled)
  __shared__ u16 Bld[3 * 8192];    // 3 x 128x64 bf16 = 48 KB (swizzled)

  const int tid  = threadIdx.x;
  const int wave = tid >> 6, lane = tid & 63;

  // T1: XCD swizzle (grid 256 = 8 XCD x 32 contiguous tiles)
  const int bid = blockIdx.x;
  const int swz = (bid & 7) * 32 + (bid >> 3);
  const int o0 = (swz >> 7) << 8;     // 0 or 256
  const int m0 = (swz & 127) << 7;    // 0..16256
  const int b  = m0 >> 10;            // uniform per block

  const int wo = (wave >> 1) * 128;   // o sub-block: 0/128
  const int wm = (wave & 1) * 64;     // m sub-block: 0/64
  const int lrow = lane & 15;
  const int lk   = (lane >> 4) * 8;
  const int rsw  = (lrow & 7) << 3;   // read-side swizzle (u16 units)
  const int kos0 = lk ^ rsw;
  const int kos1 = (32 + lk) ^ rsw;

  // staging: lane covers row (base + lane>>3), 16-B chunk (lane&7);
  // swizzled source chunk = (lane&7) ^ (row&7)  [T2 write side via global src]
  const int cc = (((lane & 7) ^ (lane >> 3)) * 8);
  // A: 8 gloads/wave (rows wave*64 + q*8), linear in q -> single base
  const u16* gAb = wbt + (size_t)(o0 + wave * 64 + (lane >> 3)) * 512 + cc;
  const int lAb = (wave * 64) * 64;                 // + q*512 (u16)
  // B: 4 gloads/wave (rows wave*32 + q*8), y/x nonlinear -> 4 ptrs
  const u16* gB[4]; int lBo[4];
  #pragma unroll
  for (int q = 0; q < 4; ++q) {
    int r = wave * 32 + q * 8 + (lane >> 3);          // 0..127
    int mg = m0 + r;
    int yy = (mg >> 5) & 31, xx = mg & 31;
    gB[q] = xsp + ((size_t)(b * PADW + yy) * PADW + xx) * 512 + cc;
    lBo[q] = (wave * 32 + q * 8) * 64;
  }

  f32x4 acc[8][4];
  #pragma unroll
  for (int i = 0; i < 8; ++i)
    #pragma unroll
    for (int j = 0; j < 4; ++j) acc[i][j] = (f32x4){0.f, 0.f, 0.f, 0.f};

  auto stgA = [&](int ks, int bufi, int q) {
    int kxy = ks >> 3, ib = (ks & 7) << 6;
    gload16(gAb + (size_t)kxy * 262144 + ib + (size_t)q * 4096,
            &Ald[bufi * 16384 + lAb + q * 512 + ib * 0]);   // dest row-major
  };
  auto stgB = [&](int ks, int bufi, int q) {
    int kxy = ks >> 3, ib = (ks & 7) << 6;
    int ky = kxy / 3, kx = kxy - ky * 3;
    gload16(gB[q] + ((ky * PADW + kx) << 9) + ib, &Bld[bufi * 8192 + lBo[q]]);
  };

#define LDA(CA, MI, KOS) (*(const short8*)&Ald[(CA) + (wo + (MI) * 16 + lrow) * 64 + (KOS)])
#define LDB(CB, NI, KOS) (*(const short8*)&Bld[(CB) + (wm + (NI) * 16 + lrow) * 64 + (KOS)])

  // phase p: av reads for mi {2p,2p+1}; 16 MFMA into acc[2p..2p+1][*]
#define PH(P, CA, STG, VMLINE)                                            \
  {                                                                       \
    short8 a0 = LDA(CA, 2*(P),   kos0), a1 = LDA(CA, 2*(P)+1, kos0);      \
    short8 a2 = LDA(CA, 2*(P),   kos1), a3 = LDA(CA, 2*(P)+1, kos1);      \
    STG;                                                                  \
    __builtin_amdgcn_s_barrier();                                         \
    __builtin_amdgcn_s_setprio(1);                                        \
    _Pragma("unroll")                                                     \
    for (int ni = 0; ni < 4; ++ni) {                                      \
      acc[2*(P)][ni]   = __builtin_amdgcn_mfma_f32_16x16x32_bf16(         \
          a0, bv0[ni], acc[2*(P)][ni], 0, 0, 0);                          \
      acc[2*(P)+1][ni] = __builtin_amdgcn_mfma_f32_16x16x32_bf16(         \
          a1, bv0[ni], acc[2*(P)+1][ni], 0, 0, 0);                        \
      acc[2*(P)][ni]   = __builtin_amdgcn_mfma_f32_16x16x32_bf16(         \
          a2, bv1[ni], acc[2*(P)][ni], 0, 0, 0);                          \
      acc[2*(P)+1][ni] = __builtin_amdgcn_mfma_f32_16x16x32_bf16(         \
          a3, bv1[ni], acc[2*(P)+1][ni], 0, 0, 0);                        \
    }                                                                     \
    __builtin_amdgcn_s_setprio(0);                                        \
    VMLINE;                                                               \
    __builtin_amdgcn_s_barrier();                                         \
  }

#define KTILE(CUR, NXT, KS2, DOSTG, VMLINE)                               \
  {                                                                       \
    const int ca = (CUR) * 16384, cb = (CUR) * 8192;                      \
    short8 bv0[4], bv1[4];                                                \
    _Pragma("unroll")                                                     \
    for (int ni = 0; ni < 4; ++ni) { bv0[ni] = LDB(cb, ni, kos0);         \
                                     bv1[ni] = LDB(cb, ni, kos1); }       \
    PH(0, ca, if (DOSTG){stgA(KS2,NXT,0);stgA(KS2,NXT,1);stgA(KS2,NXT,2);}, ) \
    PH(1, ca, if (DOSTG){stgA(KS2,NXT,3);stgA(KS2,NXT,4);stgA(KS2,NXT,5);}, ) \
    PH(2, ca, if (DOSTG){stgA(KS2,NXT,6);stgA(KS2,NXT,7);stgB(KS2,NXT,0);}, ) \
    PH(3, ca, if (DOSTG){stgB(KS2,NXT,1);stgB(KS2,NXT,2);stgB(KS2,NXT,3);}, VMLINE) \
  }

#define VM12 asm volatile("s_waitcnt vmcnt(12)" ::: "memory")
#define VM0  asm volatile("s_waitcnt vmcnt(0)"  ::: "memory")

  // prologue: tiles 0,1 staged (12 gloads each); drain tile 0, keep tile 1 in flight
  #pragma unroll
  for (int q = 0; q < 8; ++q) stgA(0, 0, q);
  #pragma unroll
  for (int q = 0; q < 4; ++q) stgB(0, 0, q);
  #pragma unroll
  for (int q = 0; q < 8; ++q) stgA(1, 1, q);
  #pragma unroll
  for (int q = 0; q < 4; ++q) stgB(1, 1, q);
  VM12;
  __builtin_amdgcn_s_barrier();

  for (int t = 0; t < 23; ++t) {
    const int k0 = t * 3;                 // tiles k0..k0+2 stage k0+2..k0+4 (<=70)
    KTILE(0, 2, k0 + 2, 1, VM12);
    KTILE(1, 0, k0 + 3, 1, VM12);
    KTILE(2, 1, k0 + 4, 1, VM12);
  }
  // tail: tiles 69,70,71
  KTILE(0, 2, 71, 1, VM12);   // tile 69: stage 71 -> buf2; drain stage(70)
  KTILE(1, 0, 0, 0, VM0);     // tile 70: drain stage(71)
  KTILE(2, 1, 0, 0, );        // tile 71
#undef KTILE
#undef PH
#undef LDA
#undef LDB
#undef VM12
#undef VM0

  // epilogue: demod*conv_scale, noise, bias, leaky(0.2)*sqrt(2)
  const float nwv = nw[0];
  const int mrow = (lane >> 4) << 2;
  #pragma unroll
  for (int mi = 0; mi < 8; ++mi) {
    #pragma unroll
    for (int ni = 0; ni < 4; ++ni) {
      int mg = m0 + wm + ni * 16 + lrow;
      int hw = mg & 1023;
      float nz = nwv * noise[b * 1024 + hw];
      #pragma unroll
      for (int r = 0; r < 4; ++r) {
        int og = o0 + wo + mi * 16 + mrow + r;
        float v = acc[mi][ni][r] * dsc[b * 512 + og] + nz + abias[og];
        v = (v > 0.f ? v : 0.2f * v) * 1.4142135623730951f;
        out[(size_t)(b * 512 + og) * 1024 + hw] = v;
      }
    }
  }
}

extern "C" void kernel_launch(void* const* d_in, const int* in_sizes, int n_in,
                              void* d_out, int out_size, void* d_ws, size_t ws_size,
                              hipStream_t stream) {
  const float* x      = (const float*)d_in[0];
  const float* style  = (const float*)d_in[1];
  const float* noise  = (const float*)d_in[2];
  const float* weight = (const float*)d_in[3];
  const float* mod_w  = (const float*)d_in[4];
  const float* mod_b  = (const float*)d_in[5];
  const float* nw     = (const float*)d_in[6];
  const float* abias  = (const float*)d_in[7];
  float* out = (float*)d_out;

  char* ws = (char*)d_ws;
  float* s_buf = (float*)(ws + WS_S);
  float* dsc   = (float*)(ws + WS_DSC);
  float* wsq   = (float*)(ws + WS_WSQ);
  u16*   wbt   = (u16*)(ws + WS_WBT);
  u16*   xsp   = (u16*)(ws + WS_XSP);

  k_halo  <<<dim3(132, 16), 256, 0, stream>>>(xsp);
  k_style <<<2048, 256, 0, stream>>>(style, mod_w, mod_b, s_buf);
  k_wprep <<<1024, 256, 0, stream>>>(weight, wsq, wbt);
  k_dscale<<<2048, 256, 0, stream>>>(wsq, s_buf, dsc);
  k_xs    <<<dim3(8, 32, 16), 256, 0, stream>>>(x, s_buf, xsp);
  k_conv  <<<256, 256, 0, stream>>>(wbt, xsp, dsc, noise, nw, abias, out);
}

// Round 14
// 123.808 us; speedup vs baseline: 1.1842x; 1.1831x over previous
//
#include <hip/hip_runtime.h>
#include <cstdint>
#include <cstddef>

typedef unsigned short u16;
typedef __attribute__((ext_vector_type(8))) short short8;
typedef __attribute__((ext_vector_type(4))) float f32x4;

#define CIN   512
#define COUT  512
#define BATCH 16
#define HWSZ  1024      // 32*32
#define PADW  34        // 32 + 2 halo

static constexpr float MOD_SCALE  = 0.044194173824159216f;   // 1/sqrt(512)
static constexpr float CONV_SCALE = 0.014731391274719739f;   // 1/sqrt(512*9)

// workspace layout (bytes)
#define WS_S    0                              // 8192 f32   (32 KB)
#define WS_DSC  (32*1024)                      // 8192 f32   (32 KB)
#define WS_WSQ  (64*1024)                      // 262144 f32 (1 MB)
#define WS_WBT  (64*1024 + 1024*1024)          // 9*512*512 bf16 (4.5 MB)
#define WS_XSP  (WS_WBT + 9*512*512*2)         // 16*34*34*512 bf16 (~18 MB)

__device__ __forceinline__ u16 f2bf(float f) {
  union { float f; uint32_t u; } v; v.f = f;
  uint32_t r = v.u + 0x7fffu + ((v.u >> 16) & 1u);   // RNE
  return (u16)(r >> 16);
}

__device__ __forceinline__ void gload16(const void* g, void* l) {
  __builtin_amdgcn_global_load_lds(
      (const __attribute__((address_space(1))) void*)g,
      (__attribute__((address_space(3))) void*)l, 16, 0, 0);
}

// ---------------- s[b,i] = mod_scale * style[b,:] . mod_w[i,:] + mod_b[i] ----------------
__global__ void k_style(const float* __restrict__ style, const float* __restrict__ mod_w,
                        const float* __restrict__ mod_b, float* __restrict__ s_out) {
  int gid  = blockIdx.x * blockDim.x + threadIdx.x;
  int w    = gid >> 6, lane = gid & 63;
  int b    = w >> 9, i = w & 511;
  const float4* st = (const float4*)(style + (size_t)b * 512);
  const float4* mw = (const float4*)(mod_w + (size_t)i * 512);
  float4 a0 = st[lane * 2], a1 = st[lane * 2 + 1];
  float4 w0 = mw[lane * 2], w1 = mw[lane * 2 + 1];
  float acc = a0.x*w0.x + a0.y*w0.y + a0.z*w0.z + a0.w*w0.w
            + a1.x*w1.x + a1.y*w1.y + a1.z*w1.z + a1.w*w1.w;
  #pragma unroll
  for (int off = 32; off; off >>= 1) acc += __shfl_xor(acc, off);
  if (lane == 0) s_out[w] = acc * MOD_SCALE + mod_b[i];
}

// ---- fused: wsq[o,i] = sum_k w^2 ; wbt2[((kxy*64 + i/8)*512 + o)*8 + i%8] = bf16(w) ----
__global__ void k_wprep(const float* __restrict__ w, float* __restrict__ wsq,
                        u16* __restrict__ wbt2) {
  int idx = blockIdx.x * 256 + threadIdx.x;          // 262144 = o*512+i
  int o = idx >> 9, i = idx & 511;
  const float* p = w + (size_t)idx * 9;
  float a = 0.f;
  #pragma unroll
  for (int kxy = 0; kxy < 9; ++kxy) {
    float v = p[kxy];
    a += v * v;
    wbt2[((size_t)(kxy * 64 + (i >> 3)) * 512 + o) * 8 + (i & 7)] = f2bf(v);
  }
  wsq[idx] = a;
}

// ---------------- dscale[b,o] = conv_scale * rsqrt(cs^2 * sum_i wsq[o,i]*s[b,i]^2 + 1e-8) ----
__global__ void k_dscale(const float* __restrict__ wsq, const float* __restrict__ s,
                         float* __restrict__ dsc) {
  int gid  = blockIdx.x * blockDim.x + threadIdx.x;
  int w    = gid >> 6, lane = gid & 63;
  int b    = w >> 9, o = w & 511;
  const float4* q4 = (const float4*)(wsq + (size_t)o * 512);
  const float4* s4 = (const float4*)(s   + (size_t)b * 512);
  float4 q0 = q4[lane * 2], q1 = q4[lane * 2 + 1];
  float4 t0 = s4[lane * 2], t1 = s4[lane * 2 + 1];
  float acc = q0.x*t0.x*t0.x + q0.y*t0.y*t0.y + q0.z*t0.z*t0.z + q0.w*t0.w*t0.w
            + q1.x*t1.x*t1.x + q1.y*t1.y*t1.y + q1.z*t1.z*t1.z + q1.w*t1.w*t1.w;
  #pragma unroll
  for (int off = 32; off; off >>= 1) acc += __shfl_xor(acc, off);
  if (lane == 0)
    dsc[w] = CONV_SCALE * rsqrtf(acc * CONV_SCALE * CONV_SCALE + 1e-8f);
}

// ---------------- zero only the halo border of xs_p ----------------
__global__ void k_halo(u16* __restrict__ xsp) {
  int cell = blockIdx.x;      // 0..131 border cells of the 34x34 grid
  int b = blockIdx.y;
  int y, x;
  if (cell < 34)       { y = 0;          x = cell; }
  else if (cell < 68)  { y = 33;         x = cell - 34; }
  else if (cell < 100) { y = cell - 67;  x = 0; }    // 1..32
  else                 { y = cell - 99;  x = 33; }   // 1..32
  uint32_t* p = (uint32_t*)(xsp + ((size_t)(b * PADW + y) * PADW + x) * 512);
  p[threadIdx.x] = 0;   // 256 threads x 4B = 512 u16
}

// ---------------- xs_p[b][y+1][x+1][i] = bf16(x[b][i][y][x] * s[b][i])  (NCHW->NHWC) --------
__global__ void k_xs(const float* __restrict__ x, const float* __restrict__ s,
                     u16* __restrict__ xsp) {
  __shared__ float tile[64][33];
  int icb = blockIdx.x, y = blockIdx.y, b = blockIdx.z;
  int t = threadIdx.x;
  int i0 = icb * 64;
  int c  = t & 31;       // x coord
  int r0 = t >> 5;       // 0..7
  #pragma unroll
  for (int it = 0; it < 8; ++it) {
    int row = r0 + it * 8;                           // i_loc 0..63
    float sv = s[b * 512 + i0 + row];
    tile[row][c] = x[((size_t)(b * 512 + i0 + row)) * 1024 + y * 32 + c] * sv;
  }
  __syncthreads();
  int il = t & 63;
  int x0 = t >> 6;       // 0..3
  #pragma unroll
  for (int it = 0; it < 8; ++it) {
    int xc = x0 + it * 4;
    xsp[((size_t)((b * PADW + y + 1) * PADW) + (xc + 1)) * 512 + i0 + il] = f2bf(tile[il][xc]);
  }
}

// ---------------- implicit-GEMM conv + fused epilogue ----------------
// R6 pipeline at HALF tile: 128(o) x 128(m), 4 waves (2o x 2m, per-wave 64x64),
// grid 512 = 2 INDEPENDENT blocks/CU (launch_bounds(256,2)) so one block's MFMA
// burst fills the other's stage/drain stalls (m97/m114 mechanism).
// A: global->VGPR direct, double-banked, 1 tile ahead (weights L2-resident, T1).
// B: tri-ring LDS (3 x 16 KB, T2 swizzled) via global_load_lds; counted
// vmcnt(8)/step: in-flight before wait = B(ks+1):4 + av(ks+1):8 = 12 ->
// drains exactly B(ks+1); stage B(ks+2) AFTER the barrier. One barrier/step.
__global__ __launch_bounds__(256, 2) void k_conv(
    const u16* __restrict__ wbt2, const u16* __restrict__ xsp,
    const float* __restrict__ dsc, const float* __restrict__ noise,
    const float* __restrict__ nw, const float* __restrict__ abias,
    float* __restrict__ out)
{
  __shared__ u16 Bld[3 * 8192];    // 3 x 128x64 bf16 = 48 KB (swizzled)

  const int tid  = threadIdx.x;
  const int wave = tid >> 6, lane = tid & 63;

  // T1: XCD swizzle (grid 512 = 8 XCD x 64 contiguous tiles; 512%8==0 bijective)
  const int bid = blockIdx.x;
  const int swz = (bid & 7) * 64 + (bid >> 3);
  const int o0 = (swz >> 7) << 7;     // 0/128/256/384
  const int m0 = (swz & 127) << 7;    // 0..16256
  const int b  = m0 >> 10;            // uniform per block

  const int wo = (wave >> 1) * 64;    // o sub-block: 0/64
  const int wm = (wave & 1) * 64;     // m sub-block: 0/64
  const int lrow = lane & 15;
  const int lk   = (lane >> 4) * 8;
  const int rsw  = (lrow & 7) << 3;   // read-side swizzle (u16 units)

  // A: per-lane global base into wbt2 fragment layout
  // addr(ks,kh,mi) = pA + (ks>>3)*262144 + (ks&7)*32768 + kh*16384 + mi*128
  const u16* pA = wbt2 + (size_t)(lane >> 4) * 4096 + (size_t)(o0 + wo + lrow) * 8;

  // B staging (global_load_lds): 4 gloads/wave, row = wave*32 + q*8 + (lane>>3),
  // swizzled source chunk = (lane&7) ^ (row&7)  [T2]
  const int cc = (((lane & 7) ^ (lane >> 3)) * 8);
  const u16* gB[4]; int lBo[4];
  #pragma unroll
  for (int q = 0; q < 4; ++q) {
    int r = wave * 32 + q * 8 + (lane >> 3);          // 0..127
    int mg = m0 + r;
    int yy = (mg >> 5) & 31, xx = mg & 31;
    gB[q] = xsp + ((size_t)(b * PADW + yy) * PADW + xx) * 512 + cc;
    lBo[q] = (wave * 32 + q * 8) * 64;
  }

  f32x4 acc[4][4];
  #pragma unroll
  for (int i = 0; i < 4; ++i)
    #pragma unroll
    for (int j = 0; j < 4; ++j) acc[i][j] = (f32x4){0.f, 0.f, 0.f, 0.f};

  short8 av0[2][4], av1[2][4];   // double-banked A fragments (64 VGPR)

  auto avload = [&](int ks, short8 (&dst)[2][4]) {
    const u16* base = pA + (size_t)(ks >> 3) * 262144 + (size_t)(ks & 7) * 32768;
    #pragma unroll
    for (int kh = 0; kh < 2; ++kh)
      #pragma unroll
      for (int mi = 0; mi < 4; ++mi)
        dst[kh][mi] = *(const short8*)(base + kh * 16384 + mi * 128);
  };

  auto stageB = [&](int ks, int bufi) {
    int kxy = ks >> 3, ib = (ks & 7) << 6;
    int ky = kxy / 3, kx = kxy - ky * 3;
    int offB = ((ky * PADW + kx) << 9) + ib;
    int sb = bufi * 8192;
    #pragma unroll
    for (int q = 0; q < 4; ++q) gload16(gB[q] + offB, &Bld[sb + lBo[q]]);
  };

  auto compute = [&](const short8 (&av)[2][4], int bufi) {
    const int cb = bufi * 8192;
    __builtin_amdgcn_s_setprio(1);
    #pragma unroll
    for (int kh = 0; kh < 2; ++kh) {
      int kos = (kh * 32 + lk) ^ rsw;
      short8 bv[4];
      #pragma unroll
      for (int ni = 0; ni < 4; ++ni)
        bv[ni] = *(const short8*)&Bld[cb + (wm + ni * 16 + lrow) * 64 + kos];
      #pragma unroll
      for (int mi = 0; mi < 4; ++mi)
        #pragma unroll
        for (int ni = 0; ni < 4; ++ni)
          acc[mi][ni] = __builtin_amdgcn_mfma_f32_16x16x32_bf16(
              av[kh][mi], bv[ni], acc[mi][ni], 0, 0, 0);
    }
    __builtin_amdgcn_s_setprio(0);
  };

  // prologue: B(0)->buf0, B(1)->buf1, A(0)->av0. In-flight: [B0:4, B1:4, av0:8]
  stageB(0, 0);
  stageB(1, 1);
  avload(0, av0);

  // Step ks: issue av(ks+1) -> other bank; vmcnt(8) [FIFO: drains everything
  // older than the 8 newest = B(ks+1) and all earlier; av(ks+1) stays in
  // flight]; barrier [all 4 waves' B(ks+1) landed -> readable at ks+1; all
  // waves done reading buf (ks+2)%3 -> overwrite safe]; stage B(ks+2);
  // compute(ks) from av bank + Bld buf ks%3.
#define STEP(KS, AVCUR, AVNXT, BBUF, BNXT, DOAV, DOSTAGE, WN)            \
  {                                                                      \
    if (DOAV) avload((KS) + 1, AVNXT);                                   \
    __builtin_amdgcn_sched_barrier(0);                                   \
    asm volatile("s_waitcnt vmcnt(" #WN ")" ::: "memory");               \
    __builtin_amdgcn_s_barrier();                                        \
    __builtin_amdgcn_sched_barrier(0);                                   \
    if (DOSTAGE) stageB((KS) + 2, BNXT);                                 \
    compute(AVCUR, BBUF);                                                \
  }

  for (int t = 0; t < 11; ++t) {
    const int k0 = t * 6;                    // ks+2 <= 67 inside: no guards
    STEP(k0 + 0, av0, av1, 0, 2, 1, 1, 8);
    STEP(k0 + 1, av1, av0, 1, 0, 1, 1, 8);
    STEP(k0 + 2, av0, av1, 2, 1, 1, 1, 8);
    STEP(k0 + 3, av1, av0, 0, 2, 1, 1, 8);
    STEP(k0 + 4, av0, av1, 1, 0, 1, 1, 8);
    STEP(k0 + 5, av1, av0, 2, 1, 1, 1, 8);
  }
  // tail ks = 66..71
  STEP(66, av0, av1, 0, 2, 1, 1, 8);
  STEP(67, av1, av0, 1, 0, 1, 1, 8);
  STEP(68, av0, av1, 2, 1, 1, 1, 8);
  STEP(69, av1, av0, 0, 2, 1, 1, 8);   // B(71) -> buf2
  STEP(70, av0, av1, 1, 0, 1, 0, 8);   // no B(72); vmcnt(8) drains B(71)
  STEP(71, av1, av0, 2, 1, 0, 0, 0);   // drain remaining
#undef STEP

  // epilogue: demod*conv_scale, noise, bias, leaky(0.2)*sqrt(2)
  const float nwv = nw[0];
  const int mrow = (lane >> 4) << 2;
  #pragma unroll
  for (int mi = 0; mi < 4; ++mi) {
    #pragma unroll
    for (int ni = 0; ni < 4; ++ni) {
      int mg = m0 + wm + ni * 16 + lrow;
      int hw = mg & 1023;
      float nz = nwv * noise[b * 1024 + hw];
      #pragma unroll
      for (int r = 0; r < 4; ++r) {
        int og = o0 + wo + mi * 16 + mrow + r;
        float v = acc[mi][ni][r] * dsc[b * 512 + og] + nz + abias[og];
        v = (v > 0.f ? v : 0.2f * v) * 1.4142135623730951f;
        out[(size_t)(b * 512 + og) * 1024 + hw] = v;
      }
    }
  }
}

extern "C" void kernel_launch(void* const* d_in, const int* in_sizes, int n_in,
                              void* d_out, int out_size, void* d_ws, size_t ws_size,
                              hipStream_t stream) {
  const float* x      = (const float*)d_in[0];
  const float* style  = (const float*)d_in[1];
  const float* noise  = (const float*)d_in[2];
  const float* weight = (const float*)d_in[3];
  const float* mod_w  = (const float*)d_in[4];
  const float* mod_b  = (const float*)d_in[5];
  const float* nw     = (const float*)d_in[6];
  const float* abias  = (const float*)d_in[7];
  float* out = (float*)d_out;

  char* ws = (char*)d_ws;
  float* s_buf = (float*)(ws + WS_S);
  float* dsc   = (float*)(ws + WS_DSC);
  float* wsq   = (float*)(ws + WS_WSQ);
  u16*   wbt2  = (u16*)(ws + WS_WBT);
  u16*   xsp   = (u16*)(ws + WS_XSP);

  k_halo  <<<dim3(132, 16), 256, 0, stream>>>(xsp);
  k_style <<<2048, 256, 0, stream>>>(style, mod_w, mod_b, s_buf);
  k_wprep <<<1024, 256, 0, stream>>>(weight, wsq, wbt2);
  k_dscale<<<2048, 256, 0, stream>>>(wsq, s_buf, dsc);
  k_xs    <<<dim3(8, 32, 16), 256, 0, stream>>>(x, s_buf, xsp);
  k_conv  <<<512, 256, 0, stream>>>(wbt2, xsp, dsc, noise, nw, abias, out);
}